// Round 10
// baseline (151.527 us; speedup 1.0000x reference)
//
#include <hip/hip_runtime.h>

// AFM layer, MI355X gfx950.
// out[b] = sum_p attn_p * s_p,  s_p = sum_d x[i,d]x[j,d]p[d]
// R7 (62.8us): 2 waves/batch. R8/R9 FAILED (237us): lambda ref-outs -> spill.
// R10 FAILED (79us): sp as 2nd MFMA chain (body tail grew; sp-dots were free).
// R11 FAILED (87us): 4 waves/batch (occupancy won't move; setup doubled).
// R12 WIN (57.0us): 1 wave = 1 batch, 0 barriers, setup amortized over 25
// bodies. R13 FAILED (83us): 2+2 MFMA split -> 2 live fx16 -> spill.
// R14 FAILED (65us): xip put sp-dots before MFMA issue -> delayed chain.
// R15 NULL (58.6us): latency cuts on the terminal path -> no gain. Model:
// per-wave latency is TLP-covered; SIMD ISSUE SLOTS are the currency.
// R16 WIN (55.7us): b64 -> b128 everywhere (STR 76->88, 176B rows: 16B
// aligned, (3r+c)%8 uniform bank-groups). Conflicts stayed 0. -5% slots
// -> -2% time. Remaining VALU/body (~64) is near algorithmic minimum.
// R17 (this round): 1-WAVE BLOCKS. block=64, grid=8192, one batch/block.
// Kernel is already barrier-free with per-wave-private LDS -> the 4-wave
// block was pure scheduling friction: block frees resources only when its
// SLOWEST wave retires; backfill and tail quantized at 4 waves. 1-wave
// blocks give wave-granular backfill + 4x finer tail; LDS cap ~22
// blocks/CU, VGPR cap 8 waves/SIMD. Probes whether occ=31% is packing.
// Pre-commit: if occupancy stays ~31%, packaging is not the limiter ->
// revert to slot deletion (2-batch setup amortization) next.
// LDS: 40 x 88 f16 = 7,040 B/block. Zero barriers.
// Pair coverage per batch (25 bodies, 780/800 slots):
//   t=1..15 : 32-rotation (nl,(nl+t)&31) all-valid (prod symmetric);
//   t=16    : half-rotation, nl<16;  t=17..24: uniform rows 32..39;
//   cleanup : 8-triangle of fields 32..39 (28 pairs, closed-form unrank).
// __launch_bounds__(64,4): same VGPR cap (128) as the proven (256,4).

typedef _Float16 f16;
typedef f16 f16x2 __attribute__((ext_vector_type(2)));
typedef f16 f16x4 __attribute__((ext_vector_type(4)));
typedef f16 f16x8 __attribute__((ext_vector_type(8)));
typedef float fx16 __attribute__((ext_vector_type(16)));

#define NF 40
#define NB 8192
#define STR 88   // f16 per LDS row (176 B): 16B-aligned b128 rows, uniform
                 // bank-group spread (3r+c mod 8) at granule level (R16)

union V8 { f16x8 v8; f16x4 v4[2]; f16x2 v2[4]; };

__global__ __launch_bounds__(64, 4) void afm_kernel(
    const float* __restrict__ x,   // [8192,40,64]
    const float* __restrict__ W1,  // [64,32]
    const float* __restrict__ b1,  // [32]
    const float* __restrict__ w2,  // [32]
    const float* __restrict__ p,   // [64]
    float* __restrict__ out)       // [8192]
{
    __shared__ __align__(16) f16 xh[NF * STR];   // 7,040 B (one batch)

    const int lane = threadIdx.x;       // block = 1 wave = 1 batch
    const int b    = blockIdx.x;

    f16* Xs = xh;

    // ---- staging: this batch (2560 floats) -> LDS f16, b128 rows ----
    // 320 granules of 8 f16 = 5 x 64 lanes exact; zero barriers in kernel.
    const float4* xb = (const float4*)(x + (size_t)b * (NF * 64));
#pragma unroll
    for (int t = 0; t < 5; ++t) {
        int g = t * 64 + lane;                 // granule 0..319 (8 f16 each)
        float4 v0 = xb[g * 2];
        float4 v1 = xb[g * 2 + 1];
        V8 w;                                   // scalar RNE converts (x8)
        w.v4[0] = f16x4{ (f16)v0.x, (f16)v0.y, (f16)v0.z, (f16)v0.w };
        w.v4[1] = f16x4{ (f16)v1.x, (f16)v1.y, (f16)v1.z, (f16)v1.w };
        int row = g >> 3, gg = g & 7;
        *(f16x8*)(Xs + row * STR + gg * 8) = w.v8;   // ds_write_b128
    }

    const int nl = lane & 31;   // MFMA column / field index base
    const int hh = lane >> 5;   // wave half -> k sub-block + a-row group
    const int h8 = hh * 8;

    // ---- A-frags: W1^T, A[m=a][k=h8+j], d = kt*16 + h8 + j ----
    f16x8 w1f[4];
#pragma unroll
    for (int kt = 0; kt < 4; ++kt)
#pragma unroll
        for (int j = 0; j < 8; ++j)
            w1f[kt][j] = (f16)W1[(kt * 16 + h8 + j) * 32 + nl];

    // ---- p packed to match prod-frag element order (for fdot2) ----
    f16x2 pp[16];
#pragma unroll
    for (int kt = 0; kt < 4; ++kt)
#pragma unroll
        for (int m = 0; m < 4; ++m) {
            f16x2 t2 = { (f16)p[kt * 16 + h8 + 2 * m], (f16)p[kt * 16 + h8 + 2 * m + 1] };
            pp[kt * 4 + m] = t2;
        }

    // ---- b1 as persistent C-frag; w2*log2e packed f16 (exp2 direct) ----
    fx16 b1C;
    f16x2 w2h[8];
#pragma unroll
    for (int r = 0; r < 16; ++r) {
        int a = (r & 3) + 8 * (r >> 2) + 4 * hh;
        b1C[r] = b1[a];
    }
#pragma unroll
    for (int m = 0; m < 8; ++m) {
        int r = 2 * m;
        int a = (r & 3) + 8 * (r >> 2) + 4 * hh;
        f16x2 t2 = { (f16)(w2[a] * 1.44269504f), (f16)(w2[a + 1] * 1.44269504f) };
        w2h[m] = t2;
    }

    // ---- xi frags for row nl: 4 x ds_read_b128 ----
    f16x8 xif8[4];
    {
        const f16* src = Xs + nl * STR + h8;
#pragma unroll
        for (int kt = 0; kt < 4; ++kt)
            xif8[kt] = *(const f16x8*)(src + kt * 16);
    }

    float accW = 0.f, accWS = 0.f;   // accWS = k-HALF sums (combined at end)

    auto body = [&](const f16x8* xi, int jrow, bool valid) {
        const f16* base = Xs + jrow * STR + h8;
        V8 pr[4];
#pragma unroll
        for (int kt = 0; kt < 4; ++kt) {
            f16x8 xj = *(const f16x8*)(base + kt * 16);        // ds_read_b128
            pr[kt].v8 = xi[kt] * xj;                           // v_pk_mul_f16 x4
        }
        // h = W1^T prod + b1 : single 4-deep chain from persistent b1 frag
        fx16 C = __builtin_amdgcn_mfma_f32_32x32x16_f16(w1f[0], pr[0].v8, b1C, 0, 0, 0);
        C = __builtin_amdgcn_mfma_f32_32x32x16_f16(w1f[1], pr[1].v8, C, 0, 0, 0);
        C = __builtin_amdgcn_mfma_f32_32x32x16_f16(w1f[2], pr[2].v8, C, 0, 0, 0);
        C = __builtin_amdgcn_mfma_f32_32x32x16_f16(w1f[3], pr[3].v8, C, 0, 0, 0);
        // s_p partial: 4 parallel fdot2 trees — in the MFMA shadow
        // (R14 lesson: AFTER the MFMA issues, not before)
        float s0 = 0.f, s1 = 0.f, s2 = 0.f, s3 = 0.f;
#pragma unroll
        for (int m = 0; m < 4; ++m) {
            s0 = __builtin_amdgcn_fdot2(pr[0].v2[m], pp[m],      s0, false);
            s1 = __builtin_amdgcn_fdot2(pr[1].v2[m], pp[4 + m],  s1, false);
            s2 = __builtin_amdgcn_fdot2(pr[2].v2[m], pp[8 + m],  s2, false);
            s3 = __builtin_amdgcn_fdot2(pr[3].v2[m], pp[12 + m], s3, false);
        }
        float sp = (s0 + s1) + (s2 + s3);                      // k-half sum
        // logit partial: relu(h).(w2*log2e) in packed f16, 2 parallel trees
        const f16x2 z2 = { (f16)0.f, (f16)0.f };
        float l0 = 0.f, l1 = 0.f;
#pragma unroll
        for (int m = 0; m < 8; ++m) {
            f16x2 hm = __builtin_bit_cast(f16x2,
                __builtin_amdgcn_cvt_pkrtz(C[2 * m], C[2 * m + 1]));
            hm = __builtin_elementwise_max(hm, z2);            // v_pk_max_f16
            if (m & 1) l1 = __builtin_amdgcn_fdot2(hm, w2h[m], l1, false);
            else       l0 = __builtin_amdgcn_fdot2(hm, w2h[m], l0, false);
        }
        float l = l0 + l1;
        l += __shfl_xor(l, 32);     // combine a-halves
        float w = __builtin_amdgcn_exp2f(l);   // max-free softmax (|l| small)
        if (!valid) w = 0.f;
        accW += w;
        accWS = fmaf(w, sp, accWS);            // k-half accumulate (no shfl)
    };

    // all 24 rotation/uniform bodies + cleanup: this batch, wave-private
    for (int t = 1; t <= 24; ++t) {
        int jrow = (t <= 16) ? ((nl + t) & 31) : (t + 15);
        bool valid = (t != 16) || (nl < 16);
        body(xif8, jrow, valid);
    }
    {   // cleanup: 28 pairs among fields 32..39 (lanes nl<28)
        int q = nl < 28 ? nl : 27;
        float disc = 225.0f - 8.0f * (float)q;
        int ii = (int)((15.0f - sqrtf(disc)) * 0.5f);
        if (ii * (15 - ii) / 2 > q) --ii;                 // sqrt 1-ulp fixups
        if ((ii + 1) * (14 - ii) / 2 <= q) ++ii;
        int jj = q - ii * (15 - ii) / 2 + ii + 1;
        int iC = 32 + ii, jC = 32 + jj;                   // pair (iC,jC), iC<jC
        f16x8 xi2[4];
        const f16* src = Xs + iC * STR + h8;
#pragma unroll
        for (int kt = 0; kt < 4; ++kt)
            xi2[kt] = *(const f16x8*)(src + kt * 16);
        body(xi2, jC, nl < 28);
    }

    // combine k-halves ONCE, then 32-column butterfly
    accWS += __shfl_xor(accWS, 32);
#pragma unroll
    for (int m = 16; m >= 1; m >>= 1) {
        accW  += __shfl_xor(accW, m);
        accWS += __shfl_xor(accWS, m);
    }
    if (lane == 0) out[b] = accWS / accW;
}

extern "C" void kernel_launch(void* const* d_in, const int* in_sizes, int n_in,
                              void* d_out, int out_size, void* d_ws, size_t ws_size,
                              hipStream_t stream) {
    const float* x  = (const float*)d_in[0];
    const float* W1 = (const float*)d_in[1];
    const float* b1 = (const float*)d_in[2];
    const float* w2 = (const float*)d_in[3];
    const float* p  = (const float*)d_in[4];
    float* out = (float*)d_out;
    dim3 grid(NB), block(64);
    hipLaunchKernelGGL(afm_kernel, grid, block, 0, stream, x, W1, b1, w2, p, out);
}

// Round 11
// 149.615 us; speedup vs baseline: 1.0128x; 1.0128x over previous
//
#include <hip/hip_runtime.h>

// AFM layer, MI355X gfx950.
// out[b] = sum_p attn_p * s_p,  s_p = sum_d x[i,d]x[j,d]p[d]
// R7 (62.8us): 2 waves/batch. R8/R9 FAILED (237us): lambda ref-outs -> spill.
// R10 FAILED (79us): sp as 2nd MFMA chain. R11 FAILED (87us): 4 waves/batch.
// R12 WIN (57.0us): 1 wave = 1 batch, 0 barriers, setup amortized over 25
// bodies. R13 FAILED (83us): 2 live fx16 -> spill. R14 FAILED (65us):
// sp-dots before MFMA issue. R15 NULL (58.6us): terminal-latency cuts.
// R16 WIN (55.7us): b64->b128 (STR 88, 0 conflicts): -5% slots -> -2% time.
// R17 NULL (56.5us): 1-wave blocks; occupancy pinned ~32% regardless of
// packaging/residency caps -> stop chasing occupancy.
// Model (R12/R14/R15/R16/R17): latency is TLP-covered at ~3 waves/SIMD;
// SIMD issue SLOTS are the currency, elasticity ~0.4 (R16). Only whole-
// block slot deletion pays.
// R18 (this round): TWO BATCHES PER WAVE. grid 4096, block 64. Setup
// (w1f/pp/b1C/w2h ~225 slots, batch-independent) hoisted out and amortized
// over 50 bodies; waves halve -> chip-wide setup work halves (~6% of slots
// -> ~2.5% predicted). LDS RE-STAGED into the same 7KB buffer between
// batches (no LDS growth, residency cap unchanged; per-wave DS queue is
// FIFO -> WAR on the buffer is safe, same wave-private pattern as R12-R17).
// Pre-commit: if dispatch >= 55us the slot model is exhausted -> stop or
// probe VALUBusy semantics before further edits.
// LDS: 40 x 88 f16 = 7,040 B/block. Zero barriers.
// Pair coverage per batch (25 bodies, 780/800 slots):
//   t=1..15 : 32-rotation (nl,(nl+t)&31) all-valid (prod symmetric);
//   t=16    : half-rotation, nl<16;  t=17..24: uniform rows 32..39;
//   cleanup : 8-triangle of fields 32..39 (28 pairs, closed-form unrank).
// __launch_bounds__(64,4): same proven VGPR regime as (256,4).

typedef _Float16 f16;
typedef f16 f16x2 __attribute__((ext_vector_type(2)));
typedef f16 f16x4 __attribute__((ext_vector_type(4)));
typedef f16 f16x8 __attribute__((ext_vector_type(8)));
typedef float fx16 __attribute__((ext_vector_type(16)));

#define NF 40
#define NB 8192
#define STR 88   // f16 per LDS row (176 B): 16B-aligned b128 rows, uniform
                 // bank-group spread (3r+c mod 8) at granule level (R16)

union V8 { f16x8 v8; f16x4 v4[2]; f16x2 v2[4]; };

__global__ __launch_bounds__(64, 4) void afm_kernel(
    const float* __restrict__ x,   // [8192,40,64]
    const float* __restrict__ W1,  // [64,32]
    const float* __restrict__ b1,  // [32]
    const float* __restrict__ w2,  // [32]
    const float* __restrict__ p,   // [64]
    float* __restrict__ out)       // [8192]
{
    __shared__ __align__(16) f16 xh[NF * STR];   // 7,040 B (one batch)

    const int lane = threadIdx.x;       // block = 1 wave; wave runs 2 batches
    const int b0   = blockIdx.x * 2;

    f16* Xs = xh;

    const int nl = lane & 31;   // MFMA column / field index base
    const int hh = lane >> 5;   // wave half -> k sub-block + a-row group
    const int h8 = hh * 8;

    // ================= batch-independent setup (ONCE per wave) =============
    // ---- A-frags: W1^T, A[m=a][k=h8+j], d = kt*16 + h8 + j ----
    f16x8 w1f[4];
#pragma unroll
    for (int kt = 0; kt < 4; ++kt)
#pragma unroll
        for (int j = 0; j < 8; ++j)
            w1f[kt][j] = (f16)W1[(kt * 16 + h8 + j) * 32 + nl];

    // ---- p packed to match prod-frag element order (for fdot2) ----
    f16x2 pp[16];
#pragma unroll
    for (int kt = 0; kt < 4; ++kt)
#pragma unroll
        for (int m = 0; m < 4; ++m) {
            f16x2 t2 = { (f16)p[kt * 16 + h8 + 2 * m], (f16)p[kt * 16 + h8 + 2 * m + 1] };
            pp[kt * 4 + m] = t2;
        }

    // ---- b1 as persistent C-frag; w2*log2e packed f16 (exp2 direct) ----
    fx16 b1C;
    f16x2 w2h[8];
#pragma unroll
    for (int r = 0; r < 16; ++r) {
        int a = (r & 3) + 8 * (r >> 2) + 4 * hh;
        b1C[r] = b1[a];
    }
#pragma unroll
    for (int m = 0; m < 8; ++m) {
        int r = 2 * m;
        int a = (r & 3) + 8 * (r >> 2) + 4 * hh;
        f16x2 t2 = { (f16)(w2[a] * 1.44269504f), (f16)(w2[a + 1] * 1.44269504f) };
        w2h[m] = t2;
    }

    // ================= per-batch loop (2 batches, re-staged LDS) ===========
#pragma unroll 1
    for (int bb = 0; bb < 2; ++bb) {
        const int b = b0 + bb;

        // ---- staging: batch b (2560 floats) -> LDS f16, b128 rows ----
        // 320 granules of 8 f16 = 5 x 64 lanes exact. Per-wave DS queue is
        // FIFO: prior batch's ds_reads retire before these ds_writes (WAR ok).
        const float4* xb = (const float4*)(x + (size_t)b * (NF * 64));
#pragma unroll
        for (int t = 0; t < 5; ++t) {
            int g = t * 64 + lane;             // granule 0..319 (8 f16 each)
            float4 v0 = xb[g * 2];
            float4 v1 = xb[g * 2 + 1];
            V8 w;                               // scalar RNE converts (x8)
            w.v4[0] = f16x4{ (f16)v0.x, (f16)v0.y, (f16)v0.z, (f16)v0.w };
            w.v4[1] = f16x4{ (f16)v1.x, (f16)v1.y, (f16)v1.z, (f16)v1.w };
            int row = g >> 3, gg = g & 7;
            *(f16x8*)(Xs + row * STR + gg * 8) = w.v8;   // ds_write_b128
        }

        // ---- xi frags for row nl: 4 x ds_read_b128 ----
        f16x8 xif8[4];
        {
            const f16* src = Xs + nl * STR + h8;
#pragma unroll
            for (int kt = 0; kt < 4; ++kt)
                xif8[kt] = *(const f16x8*)(src + kt * 16);
        }

        float accW = 0.f, accWS = 0.f;   // accWS = k-HALF sums

        auto body = [&](const f16x8* xi, int jrow, bool valid) {
            const f16* base = Xs + jrow * STR + h8;
            V8 pr[4];
#pragma unroll
            for (int kt = 0; kt < 4; ++kt) {
                f16x8 xj = *(const f16x8*)(base + kt * 16);    // ds_read_b128
                pr[kt].v8 = xi[kt] * xj;                       // v_pk_mul_f16 x4
            }
            // h = W1^T prod + b1 : single 4-deep chain (one live fx16, R13)
            fx16 C = __builtin_amdgcn_mfma_f32_32x32x16_f16(w1f[0], pr[0].v8, b1C, 0, 0, 0);
            C = __builtin_amdgcn_mfma_f32_32x32x16_f16(w1f[1], pr[1].v8, C, 0, 0, 0);
            C = __builtin_amdgcn_mfma_f32_32x32x16_f16(w1f[2], pr[2].v8, C, 0, 0, 0);
            C = __builtin_amdgcn_mfma_f32_32x32x16_f16(w1f[3], pr[3].v8, C, 0, 0, 0);
            // s_p partial: 4 parallel fdot2 trees — in the MFMA shadow (R14)
            float s0 = 0.f, s1 = 0.f, s2 = 0.f, s3 = 0.f;
#pragma unroll
            for (int m = 0; m < 4; ++m) {
                s0 = __builtin_amdgcn_fdot2(pr[0].v2[m], pp[m],      s0, false);
                s1 = __builtin_amdgcn_fdot2(pr[1].v2[m], pp[4 + m],  s1, false);
                s2 = __builtin_amdgcn_fdot2(pr[2].v2[m], pp[8 + m],  s2, false);
                s3 = __builtin_amdgcn_fdot2(pr[3].v2[m], pp[12 + m], s3, false);
            }
            float sp = (s0 + s1) + (s2 + s3);                  // k-half sum
            // logit partial: relu(h).(w2*log2e), packed f16, 2 trees
            const f16x2 z2 = { (f16)0.f, (f16)0.f };
            float l0 = 0.f, l1 = 0.f;
#pragma unroll
            for (int m = 0; m < 8; ++m) {
                f16x2 hm = __builtin_bit_cast(f16x2,
                    __builtin_amdgcn_cvt_pkrtz(C[2 * m], C[2 * m + 1]));
                hm = __builtin_elementwise_max(hm, z2);        // v_pk_max_f16
                if (m & 1) l1 = __builtin_amdgcn_fdot2(hm, w2h[m], l1, false);
                else       l0 = __builtin_amdgcn_fdot2(hm, w2h[m], l0, false);
            }
            float l = l0 + l1;
            l += __shfl_xor(l, 32);     // combine a-halves
            float w = __builtin_amdgcn_exp2f(l);   // max-free softmax
            if (!valid) w = 0.f;
            accW += w;
            accWS = fmaf(w, sp, accWS);            // k-half accumulate
        };

        // all 24 rotation/uniform bodies + cleanup: wave-private
        for (int t = 1; t <= 24; ++t) {
            int jrow = (t <= 16) ? ((nl + t) & 31) : (t + 15);
            bool valid = (t != 16) || (nl < 16);
            body(xif8, jrow, valid);
        }
        {   // cleanup: 28 pairs among fields 32..39 (lanes nl<28)
            int q = nl < 28 ? nl : 27;
            float disc = 225.0f - 8.0f * (float)q;
            int ii = (int)((15.0f - sqrtf(disc)) * 0.5f);
            if (ii * (15 - ii) / 2 > q) --ii;             // sqrt 1-ulp fixups
            if ((ii + 1) * (14 - ii) / 2 <= q) ++ii;
            int jj = q - ii * (15 - ii) / 2 + ii + 1;
            int iC = 32 + ii, jC = 32 + jj;               // pair (iC,jC), iC<jC
            f16x8 xi2[4];
            const f16* src = Xs + iC * STR + h8;
#pragma unroll
            for (int kt = 0; kt < 4; ++kt)
                xi2[kt] = *(const f16x8*)(src + kt * 16);
            body(xi2, jC, nl < 28);
        }

        // combine k-halves ONCE, then 32-column butterfly
        accWS += __shfl_xor(accWS, 32);
#pragma unroll
        for (int m = 16; m >= 1; m >>= 1) {
            accW  += __shfl_xor(accW, m);
            accWS += __shfl_xor(accWS, m);
        }
        if (lane == 0) out[b] = accWS / accW;
    }
}

extern "C" void kernel_launch(void* const* d_in, const int* in_sizes, int n_in,
                              void* d_out, int out_size, void* d_ws, size_t ws_size,
                              hipStream_t stream) {
    const float* x  = (const float*)d_in[0];
    const float* W1 = (const float*)d_in[1];
    const float* b1 = (const float*)d_in[2];
    const float* w2 = (const float*)d_in[3];
    const float* p  = (const float*)d_in[4];
    float* out = (float*)d_out;
    dim3 grid(NB / 2), block(64);
    hipLaunchKernelGGL(afm_kernel, grid, block, 0, stream, x, W1, b1, w2, p, out);
}

// Round 12
// 147.953 us; speedup vs baseline: 1.0242x; 1.0112x over previous
//
#include <hip/hip_runtime.h>

// AFM layer, MI355X gfx950.
// out[b] = sum_p attn_p * s_p,  s_p = sum_d x[i,d]x[j,d]p[d]
// History: R7 62.8 (2 waves/batch) | R8/R9 237 FAILED lambda-ref spill |
// R10 79 FAILED sp-as-MFMA | R11 87 FAILED 4 waves/batch | R12 57.0 WIN
// (1 wave = 1 batch, 0 barriers) | R13 83 FAILED 2 live fx16 spill |
// R14 65 FAILED sp-dots before MFMA | R15 58.6 NULL latency cuts |
// R16 55.7 WIN b64->b128 (STR 88, 0 conflicts) | R17 56.5 NULL 1-wave
// blocks (occupancy pinned ~30-32% at ANY packaging) | R18 57.4 NULL/NEG
// 2 batches/wave (setup halved but resident waves fell; mid-wave restage
// serializes). Model: resident waves ~2.5-3/SIMD immovable; time tracks
// issue slots (elasticity ~0.4); latency cuts null.
// R19 (this round): R16 base +
//   a. T5 s_setprio(1) around MFMA chain + sp shadow, setprio(0) for the
//      logit tail. This kernel is the attn-like independent-wave case
//      (m191: +4-7%), NOT the lockstep-GEMM null case (m190). 2 SALU/body.
//   b. valid-check hoisted: t=1..15 and t=17..24 are always-valid; only
//      t=16 and cleanup masked. Removes cmp+cndmask from 23/25 bodies.
// Pre-commit: if dispatch >= 55us, slot+catalog levers are exhausted ->
// declare practical floor.
// LDS: 4 x 40 x 88 f16 = 28,160 B. Zero barriers (per-wave private slices).
// Pair coverage per batch (25 bodies, 780/800 slots):
//   t=1..15 : 32-rotation (nl,(nl+t)&31) all-valid (prod symmetric);
//   t=16    : half-rotation, nl<16;  t=17..24: uniform rows 32..39;
//   cleanup : 8-triangle of fields 32..39 (28 pairs, closed-form unrank).
// __launch_bounds__(256,4): VGPR cap 128, lands at 64 (proven since R12).

typedef _Float16 f16;
typedef f16 f16x2 __attribute__((ext_vector_type(2)));
typedef f16 f16x4 __attribute__((ext_vector_type(4)));
typedef f16 f16x8 __attribute__((ext_vector_type(8)));
typedef float fx16 __attribute__((ext_vector_type(16)));

#define NF 40
#define NB 8192
#define STR 88   // f16 per LDS row (176 B): 16B-aligned b128 rows, uniform
                 // bank-group spread (3r+c mod 8) at granule level (R16)

union V8 { f16x8 v8; f16x4 v4[2]; f16x2 v2[4]; };

__global__ __launch_bounds__(256, 4) void afm_kernel(
    const float* __restrict__ x,   // [8192,40,64]
    const float* __restrict__ W1,  // [64,32]
    const float* __restrict__ b1,  // [32]
    const float* __restrict__ w2,  // [32]
    const float* __restrict__ p,   // [64]
    float* __restrict__ out)       // [8192]
{
    __shared__ __align__(16) f16 xh[4][NF * STR];   // 28,160 B

    const int tid  = threadIdx.x;
    const int wid  = tid >> 6;          // wave -> private batch
    const int lane = tid & 63;
    const int b    = blockIdx.x * 4 + wid;

    f16* Xs = &xh[wid][0];

    // ---- per-wave staging: this wave's batch only (2560 floats) ----
    // 320 granules of 8 f16 = 5 x 64 lanes exact; zero barriers in kernel.
    const float4* xb = (const float4*)(x + (size_t)b * (NF * 64));
#pragma unroll
    for (int t = 0; t < 5; ++t) {
        int g = t * 64 + lane;                 // granule 0..319 (8 f16 each)
        float4 v0 = xb[g * 2];
        float4 v1 = xb[g * 2 + 1];
        V8 w;                                   // scalar RNE converts (x8)
        w.v4[0] = f16x4{ (f16)v0.x, (f16)v0.y, (f16)v0.z, (f16)v0.w };
        w.v4[1] = f16x4{ (f16)v1.x, (f16)v1.y, (f16)v1.z, (f16)v1.w };
        int row = g >> 3, gg = g & 7;
        *(f16x8*)(Xs + row * STR + gg * 8) = w.v8;   // ds_write_b128
    }

    const int nl = lane & 31;   // MFMA column / field index base
    const int hh = lane >> 5;   // wave half -> k sub-block + a-row group
    const int h8 = hh * 8;

    // ---- A-frags: W1^T, A[m=a][k=h8+j], d = kt*16 + h8 + j ----
    f16x8 w1f[4];
#pragma unroll
    for (int kt = 0; kt < 4; ++kt)
#pragma unroll
        for (int j = 0; j < 8; ++j)
            w1f[kt][j] = (f16)W1[(kt * 16 + h8 + j) * 32 + nl];

    // ---- p packed to match prod-frag element order (for fdot2) ----
    f16x2 pp[16];
#pragma unroll
    for (int kt = 0; kt < 4; ++kt)
#pragma unroll
        for (int m = 0; m < 4; ++m) {
            f16x2 t2 = { (f16)p[kt * 16 + h8 + 2 * m], (f16)p[kt * 16 + h8 + 2 * m + 1] };
            pp[kt * 4 + m] = t2;
        }

    // ---- b1 as persistent C-frag; w2*log2e packed f16 (exp2 direct) ----
    fx16 b1C;
    f16x2 w2h[8];
#pragma unroll
    for (int r = 0; r < 16; ++r) {
        int a = (r & 3) + 8 * (r >> 2) + 4 * hh;
        b1C[r] = b1[a];
    }
#pragma unroll
    for (int m = 0; m < 8; ++m) {
        int r = 2 * m;
        int a = (r & 3) + 8 * (r >> 2) + 4 * hh;
        f16x2 t2 = { (f16)(w2[a] * 1.44269504f), (f16)(w2[a + 1] * 1.44269504f) };
        w2h[m] = t2;
    }

    // ---- xi frags for row nl: 4 x ds_read_b128 ----
    f16x8 xif8[4];
    {
        const f16* src = Xs + nl * STR + h8;
#pragma unroll
        for (int kt = 0; kt < 4; ++kt)
            xif8[kt] = *(const f16x8*)(src + kt * 16);
    }

    float accW = 0.f, accWS = 0.f;   // accWS = k-HALF sums (combined at end)

    // MASK=false: always-valid body (no cmp/cndmask — 23 of 25 bodies)
    auto body = [&](const f16x8* xi, int jrow, bool mask, bool valid) {
        const f16* base = Xs + jrow * STR + h8;
        V8 pr[4];
#pragma unroll
        for (int kt = 0; kt < 4; ++kt) {
            f16x8 xj = *(const f16x8*)(base + kt * 16);        // ds_read_b128
            pr[kt].v8 = xi[kt] * xj;                           // v_pk_mul_f16 x4
        }
        // T5: boost priority through the MFMA chain + its shadow work
        __builtin_amdgcn_s_setprio(1);
        // h = W1^T prod + b1 : single 4-deep chain from persistent b1 frag
        fx16 C = __builtin_amdgcn_mfma_f32_32x32x16_f16(w1f[0], pr[0].v8, b1C, 0, 0, 0);
        C = __builtin_amdgcn_mfma_f32_32x32x16_f16(w1f[1], pr[1].v8, C, 0, 0, 0);
        C = __builtin_amdgcn_mfma_f32_32x32x16_f16(w1f[2], pr[2].v8, C, 0, 0, 0);
        C = __builtin_amdgcn_mfma_f32_32x32x16_f16(w1f[3], pr[3].v8, C, 0, 0, 0);
        // s_p partial: 4 parallel fdot2 trees — in the MFMA shadow (R14)
        float s0 = 0.f, s1 = 0.f, s2 = 0.f, s3 = 0.f;
#pragma unroll
        for (int m = 0; m < 4; ++m) {
            s0 = __builtin_amdgcn_fdot2(pr[0].v2[m], pp[m],      s0, false);
            s1 = __builtin_amdgcn_fdot2(pr[1].v2[m], pp[4 + m],  s1, false);
            s2 = __builtin_amdgcn_fdot2(pr[2].v2[m], pp[8 + m],  s2, false);
            s3 = __builtin_amdgcn_fdot2(pr[3].v2[m], pp[12 + m], s3, false);
        }
        __builtin_amdgcn_s_setprio(0);
        float sp = (s0 + s1) + (s2 + s3);                      // k-half sum
        // logit partial: relu(h).(w2*log2e) in packed f16, 2 parallel trees
        const f16x2 z2 = { (f16)0.f, (f16)0.f };
        float l0 = 0.f, l1 = 0.f;
#pragma unroll
        for (int m = 0; m < 8; ++m) {
            f16x2 hm = __builtin_bit_cast(f16x2,
                __builtin_amdgcn_cvt_pkrtz(C[2 * m], C[2 * m + 1]));
            hm = __builtin_elementwise_max(hm, z2);            // v_pk_max_f16
            if (m & 1) l1 = __builtin_amdgcn_fdot2(hm, w2h[m], l1, false);
            else       l0 = __builtin_amdgcn_fdot2(hm, w2h[m], l0, false);
        }
        float l = l0 + l1;
        l += __shfl_xor(l, 32);     // combine a-halves
        float w = __builtin_amdgcn_exp2f(l);   // max-free softmax (|l| small)
        if (mask && !valid) w = 0.f;           // only t=16 + cleanup pay this
        accW += w;
        accWS = fmaf(w, sp, accWS);            // k-half accumulate (no shfl)
    };

    // t = 1..15: full rotation, ALWAYS valid (each pair diff t once)
    for (int t = 1; t <= 15; ++t)
        body(xif8, (nl + t) & 31, false, true);
    // t = 16: half rotation, masked (nl < 16)
    body(xif8, (nl + 16) & 31, true, nl < 16);
    // t = 17..24: uniform rows 32..39, ALWAYS valid
    for (int t = 17; t <= 24; ++t)
        body(xif8, t + 15, false, true);
    {   // cleanup: 28 pairs among fields 32..39 (lanes nl<28), masked
        int q = nl < 28 ? nl : 27;
        float disc = 225.0f - 8.0f * (float)q;
        int ii = (int)((15.0f - sqrtf(disc)) * 0.5f);
        if (ii * (15 - ii) / 2 > q) --ii;                 // sqrt 1-ulp fixups
        if ((ii + 1) * (14 - ii) / 2 <= q) ++ii;
        int jj = q - ii * (15 - ii) / 2 + ii + 1;
        int iC = 32 + ii, jC = 32 + jj;                   // pair (iC,jC), iC<jC
        f16x8 xi2[4];
        const f16* src = Xs + iC * STR + h8;
#pragma unroll
        for (int kt = 0; kt < 4; ++kt)
            xi2[kt] = *(const f16x8*)(src + kt * 16);
        body(xi2, jC, true, nl < 28);
    }

    // combine k-halves ONCE, then 32-column butterfly
    accWS += __shfl_xor(accWS, 32);
#pragma unroll
    for (int m = 16; m >= 1; m >>= 1) {
        accW  += __shfl_xor(accW, m);
        accWS += __shfl_xor(accWS, m);
    }
    if (lane == 0) out[b] = accWS / accW;
}

extern "C" void kernel_launch(void* const* d_in, const int* in_sizes, int n_in,
                              void* d_out, int out_size, void* d_ws, size_t ws_size,
                              hipStream_t stream) {
    const float* x  = (const float*)d_in[0];
    const float* W1 = (const float*)d_in[1];
    const float* b1 = (const float*)d_in[2];
    const float* w2 = (const float*)d_in[3];
    const float* p  = (const float*)d_in[4];
    float* out = (float*)d_out;
    dim3 grid(NB / 4), block(256);
    hipLaunchKernelGGL(afm_kernel, grid, block, 0, stream, x, W1, b1, w2, p, out);
}